// Round 2
// baseline (419.779 us; speedup 1.0000x reference)
//
#include <hip/hip_runtime.h>
#include <hip/hip_bf16.h>

typedef __attribute__((ext_vector_type(8))) short bf16x8_t;
typedef __attribute__((ext_vector_type(4))) float f32x4_t;

#define XP_BYTES 55115776u   // 4*16*58*58*128*2
#define WT_BYTES 4718592u    // 4*2*256*1152*2

typedef __attribute__((address_space(1))) const unsigned int ga_u32_t;
typedef __attribute__((address_space(3))) unsigned int lds_u32_t;

__device__ __forceinline__ void g2l16(const void* g, void* l) {
  __builtin_amdgcn_global_load_lds((ga_u32_t*)g, (lds_u32_t*)l, 16, 0, 0);
}

// ---------------------------------------------------------------------------
// prep_x: x (16,256,56,56) f32  ->  xp (4,16,58,58,128) bf16, inner = hl*64+c
// borders zeroed by hipMemsetAsync before this kernel.
// ---------------------------------------------------------------------------
__global__ __launch_bounds__(256) void prep_x(const float* __restrict__ x,
                                              __hip_bfloat16* __restrict__ xp) {
  __shared__ float ls[64 * 57];
  int blk = blockIdx.x;            // (g, b, h) : 4*16*56 = 3584
  int g = blk / 896;
  int r = blk - g * 896;
  int b = r / 56;
  int h = r - b * 56;
  int tid = threadIdx.x;
  const float* src = x + (size_t)(b * 256 + g * 64) * 3136 + h * 56;
  for (int i = tid; i < 64 * 56; i += 256) {
    int c = i / 56, w = i - c * 56;
    ls[c * 57 + w] = src[(size_t)c * 3136 + w];
  }
  __syncthreads();
  __hip_bfloat16* dst = xp + ((size_t)((g * 16 + b) * 58 + h + 1) * 58 + 1) * 128;
  int wp = tid >> 7;
  int inner = tid & 127;
  int hl = inner >> 6, c = inner & 63;
  for (int w0 = 0; w0 < 56; w0 += 2) {
    int w = w0 + wp;
    float v = ls[c * 57 + w];
    __hip_bfloat16 hi = __float2bfloat16(v);
    __hip_bfloat16 val = hl ? __float2bfloat16(v - __bfloat162float(hi)) : hi;
    dst[(size_t)w * 128 + inner] = val;
  }
}

// ---------------------------------------------------------------------------
// prep_w: weight (256,256,3,3) f32 -> wt[g][NB=2][n=2*ocl+sign (256)][k=1152]
// integer quant levels 0..3 as bf16 (exact), duplicated for hl=0/1.
// ---------------------------------------------------------------------------
__global__ __launch_bounds__(256) void prep_w(const float* __restrict__ wgt,
                                              const float* __restrict__ wsc,
                                              __hip_bfloat16* __restrict__ wt) {
  int idx = blockIdx.x * 256 + threadIdx.x;   // 589824
  if (idx >= 589824) return;
  int oc = idx / 2304;
  int r = idx - oc * 2304;
  int C = r / 9;
  int tap = r - C * 9;
  int g = C >> 6, c = C & 63;
  float s = wsc[g];
  float rv = wgt[idx] / s;
  float ip = rintf(fminf(fmaxf(rv, 0.f), 3.f));
  float iN = rintf(fminf(fmaxf(-rv, 0.f), 3.f));
  int nb2 = oc >> 7, ocl = oc & 127;
  size_t base = ((size_t)((g * 2 + nb2) * 256 + 2 * ocl)) * 1152 + tap * 128 + c;
  __hip_bfloat16 vp = __float2bfloat16(ip);
  __hip_bfloat16 vn = __float2bfloat16(iN);
  wt[base] = vp;
  wt[base + 64] = vp;
  wt[base + 1152] = vn;
  wt[base + 1152 + 64] = vn;
}

// ---------------------------------------------------------------------------
// Main implicit-GEMM conv. BM=128 (spatial), BN=256 (128 oc x 2 signs),
// 512 threads = 8 waves (2M x 4N), per-wave 64x64. K-step 64 split in two
// 32-wide kk planes; 4-phase/iter schedule, counted vmcnt(3), setprio MFMA.
// LDS plane layout [rows][64B] -> 2-way bank aliasing (free) on ds_read_b128.
// ---------------------------------------------------------------------------
#define MEMPIN asm volatile("" ::: "memory")
#define BAR __builtin_amdgcn_s_barrier()
#define VMCNT3 asm volatile("s_waitcnt vmcnt(3)" ::: "memory")
#define VMCNT0 asm volatile("s_waitcnt vmcnt(0)" ::: "memory")

__global__ __launch_bounds__(512, 2) void conv_mfma(
    const unsigned short* __restrict__ xp, const unsigned short* __restrict__ wt,
    const float* __restrict__ wsc, const float* __restrict__ psp,
    const float* __restrict__ psn, float* __restrict__ out) {
  // A: [dbuf][kk][128 rows][32k]  -> 2*2*8KB = 32KB
  // B: [dbuf][kk][256 rows][32k]  -> 2*2*16KB = 64KB
  __shared__ char As_[32768];
  __shared__ char Bs_[65536];

  const int bid = blockIdx.x;
  const int wg = (bid & 7) * 98 + (bid >> 3);     // bijective XCD swizzle (784=8*98)
  const int NB = wg / 392;                        // 2 N-tiles
  const int mblk = wg - NB * 392;                 // 392 M-tiles

  const int tid = threadIdx.x;
  const int wv = tid >> 6;
  const int l = tid & 63;
  const int wr = wv >> 2, wc = wv & 3;

  // ---- staging source offsets (thread tid covers LDS byte tid*16 of a unit)
  unsigned aoff, boff0, boff1;
  {
    int m = mblk * 128 + (tid >> 2);
    int b = m / 3136;
    int hw = m - b * 3136;
    int h = hw / 56;
    int w = hw - h * 56;
    aoff = (unsigned)((b * 3364 + h * 58 + w) * 256) + ((tid & 3) << 4);
    unsigned nbase = (unsigned)(NB * 589824) + ((tid & 3) << 4);
    boff0 = nbase + (unsigned)((tid >> 2) * 2304);
    boff1 = nbase + (unsigned)(((tid >> 2) + 128) * 2304);
  }

  // ---- fragment read offsets within a plane
  const int a_rd = (wr * 64 + (l & 15)) * 64 + ((l >> 4) << 4);
  const int b_rd = (wc * 64 + (l & 15)) * 64 + ((l >> 4) << 4);

  // ---- preload all scalars as named regs (no vector loads inside the loop!)
  float w0s = wsc[0], w1s = wsc[1], w2s = wsc[2], w3s = wsc[3];
  float p0 = psp[0], p1 = psp[1], p2 = psp[2], p3 = psp[3];
  float n0 = psn[0], n1 = psn[1], n2 = psn[2], n3 = psn[3];

  f32x4_t acc[4][4], oacc[4][4];
  const f32x4_t fz = {0.f, 0.f, 0.f, 0.f};
#pragma unroll
  for (int i = 0; i < 4; ++i)
#pragma unroll
    for (int j = 0; j < 4; ++j) { acc[i][j] = fz; oacc[i][j] = fz; }

  const char* xg = (const char*)xp;
  const char* wgp = (const char*)wt;

  // stage one kk-plane of tile t: A unit (8KB) + 2 B units (16KB), 3 g2l16/thread
#define STAGE3(t, kk)                                                          \
  {                                                                            \
    int g_ = (t) / 18, s_ = (t) - g_ * 18;                                     \
    int tap_ = s_ >> 1, hl_ = s_ & 1;                                          \
    unsigned at_ = (unsigned)(g_ * 13778944) +                                 \
                   (unsigned)(((tap_ / 3) * 58 + (tap_ % 3)) << 8) +           \
                   (unsigned)(hl_ << 7) + (unsigned)((kk) << 6);               \
    unsigned bt_ = (unsigned)(g_ * 1179648) + ((unsigned)s_ << 7) +            \
                   (unsigned)((kk) << 6);                                      \
    char* lA_ = As_ + (((t) & 1) << 14) + ((kk) << 13) + (wv << 10);           \
    char* lB_ = Bs_ + (((t) & 1) << 15) + ((kk) << 14) + (wv << 10);           \
    g2l16(xg + aoff + at_, lA_);                                               \
    g2l16(wgp + boff0 + bt_, lB_);                                             \
    g2l16(wgp + boff1 + bt_, lB_ + 8192);                                      \
  }

#define PHASE_READ(ab, bb)                                                     \
  _Pragma("unroll") for (int mi = 0; mi < 4; ++mi)                             \
      af[mi] = *(const bf16x8_t*)(As_ + (ab) + a_rd + mi * 1024);              \
  _Pragma("unroll") for (int ni = 0; ni < 4; ++ni)                             \
      bf[ni] = *(const bf16x8_t*)(Bs_ + (bb) + b_rd + ni * 1024);

#define PHASE_MMA                                                              \
  __builtin_amdgcn_s_setprio(1);                                               \
  _Pragma("unroll") for (int mi = 0; mi < 4; ++mi)                             \
      _Pragma("unroll") for (int ni = 0; ni < 4; ++ni)                         \
          acc[mi][ni] = __builtin_amdgcn_mfma_f32_16x16x32_bf16(               \
              af[mi], bf[ni], acc[mi][ni], 0, 0, 0);                           \
  __builtin_amdgcn_s_setprio(0);

  // ---- prologue: tile0 kk0, tile0 kk1, tile1 kk0 issued; keep 3 in flight
  STAGE3(0, 0);
  STAGE3(0, 1);
  STAGE3(1, 0);
  VMCNT3;
  BAR;

  for (int i = 0; i < 36; ++i) {
    const int t = 2 * i;
    bf16x8_t af[4], bf[4];
    // phase 1: compute tile t kk0 (buf0 p0); stage tile t+1 kk1 (buf1 p1)
    PHASE_READ(0, 0);
    MEMPIN;
    STAGE3(t + 1, 1);
    BAR;
    PHASE_MMA;
    BAR;
    // phase 2: compute tile t kk1 (buf0 p1); stage tile t+2 kk0 (buf0 p0)
    PHASE_READ(8192, 16384);
    MEMPIN;
    if (t < 70) { STAGE3(t + 2, 0); }
    if (t == 70) { VMCNT0; } else { VMCNT3; }
    BAR;
    PHASE_MMA;
    BAR;
    // phase 3: compute tile t+1 kk0 (buf1 p0); stage tile t+2 kk1 (buf0 p1)
    PHASE_READ(16384, 32768);
    MEMPIN;
    if (t < 70) { STAGE3(t + 2, 1); }
    BAR;
    PHASE_MMA;
    BAR;
    // phase 4: compute tile t+1 kk1 (buf1 p1); stage tile t+3 kk0 (buf1 p0)
    PHASE_READ(16384 + 8192, 32768 + 16384);
    MEMPIN;
    if (t < 70) { STAGE3(t + 3, 0); }
    VMCNT3;
    BAR;
    PHASE_MMA;
    BAR;

    if ((i % 9) == 8) {                // group boundary: quantize psums
      int gg = i / 9;
      float sw = (gg & 2) ? ((gg & 1) ? w3s : w2s) : ((gg & 1) ? w1s : w0s);
      float sp = (gg & 2) ? ((gg & 1) ? p3 : p2) : ((gg & 1) ? p1 : p0);
      float sn = (gg & 2) ? ((gg & 1) ? n3 : n2) : ((gg & 1) ? n1 : n0);
      float smine = (l & 1) ? sn : sp;
      float rs = sw / smine;
#pragma unroll
      for (int mi = 0; mi < 4; ++mi)
#pragma unroll
        for (int ni = 0; ni < 4; ++ni)
#pragma unroll
          for (int j = 0; j < 4; ++j) {
            float v = acc[mi][ni][j] * rs;
            v = fminf(fmaxf(v, -128.f), 127.f);
            v = rintf(v) * smine;
            float o = __shfl_xor(v, 1);
            oacc[mi][ni][j] += (l & 1) ? (o - v) : (v - o);
            acc[mi][ni][j] = 0.f;
          }
    }
  }

  // write: even lanes hold (p - n) for oc = NB*128 + col/2
  if (!(l & 1)) {
#pragma unroll
    for (int ni = 0; ni < 4; ++ni) {
      int col = wc * 64 + ni * 16 + (l & 15);
      int oc = NB * 128 + (col >> 1);
#pragma unroll
      for (int mi = 0; mi < 4; ++mi) {
        int m0 = mblk * 128 + wr * 64 + mi * 16 + ((l >> 4) << 2);
#pragma unroll
        for (int j = 0; j < 4; ++j) {
          int m = m0 + j;
          int b = m / 3136;
          int hw = m - b * 3136;
          out[(size_t)((b << 8) + oc) * 3136 + hw] = oacc[mi][ni][j];
        }
      }
    }
  }
#undef STAGE3
#undef PHASE_READ
#undef PHASE_MMA
}

// ---------------------------------------------------------------------------
// Fallback (ws too small): direct conv with inline weight quantization.
// ---------------------------------------------------------------------------
__global__ __launch_bounds__(256) void naive_conv(
    const float* __restrict__ x, const float* __restrict__ wgt,
    const float* __restrict__ wsc, const float* __restrict__ psp,
    const float* __restrict__ psn, float* __restrict__ out) {
  int idx = blockIdx.x * 256 + threadIdx.x;
  if (idx >= 12845056) return;
  int b = idx / 802816;
  int r = idx - b * 802816;
  int oc = r / 3136;
  int hw = r - oc * 3136;
  int h = hw / 56, w = hw - (hw / 56) * 56;
  float o = 0.f;
  for (int g = 0; g < 4; ++g) {
    float sw = wsc[g];
    float inv = 1.f / sw;
    float pp = 0.f, pn = 0.f;
    for (int tap = 0; tap < 9; ++tap) {
      int y = h + tap / 3 - 1, xx = w + tap % 3 - 1;
      if (y < 0 || y > 55 || xx < 0 || xx > 55) continue;
      const float* xr = x + (size_t)(b * 256 + g * 64) * 3136 + y * 56 + xx;
      const float* wrr = wgt + (size_t)oc * 2304 + (size_t)(g * 64) * 9 + tap;
      for (int c = 0; c < 64; ++c) {
        float xv = xr[(size_t)c * 3136];
        float rv = wrr[c * 9] * inv;
        pp += xv * rintf(fminf(fmaxf(rv, 0.f), 3.f));
        pn += xv * rintf(fminf(fmaxf(-rv, 0.f), 3.f));
      }
    }
    float sp = psp[g], sn = psn[g];
    o += rintf(fminf(fmaxf(pp * (sw / sp), -128.f), 127.f)) * sp;
    o -= rintf(fminf(fmaxf(pn * (sw / sn), -128.f), 127.f)) * sn;
  }
  out[idx] = o;
}

extern "C" void kernel_launch(void* const* d_in, const int* in_sizes, int n_in,
                              void* d_out, int out_size, void* d_ws, size_t ws_size,
                              hipStream_t stream) {
  const float* x = (const float*)d_in[0];
  const float* wgt = (const float*)d_in[1];
  const float* wsc = (const float*)d_in[2];
  const float* psp = (const float*)d_in[3];
  const float* psn = (const float*)d_in[4];
  float* out = (float*)d_out;

  if (ws_size >= (size_t)XP_BYTES + (size_t)WT_BYTES) {
    unsigned short* xpw = (unsigned short*)d_ws;
    unsigned short* wtw = (unsigned short*)((char*)d_ws + XP_BYTES);
    hipMemsetAsync(d_ws, 0, XP_BYTES, stream);
    prep_x<<<3584, 256, 0, stream>>>(x, (__hip_bfloat16*)xpw);
    prep_w<<<2304, 256, 0, stream>>>(wgt, wsc, (__hip_bfloat16*)wtw);
    conv_mfma<<<784, 512, 0, stream>>>(xpw, wtw, wsc, psp, psn, out);
  } else {
    naive_conv<<<(12845056 + 255) / 256, 256, 0, stream>>>(x, wgt, wsc, psp, psn, out);
  }
}

// Round 3
// 293.059 us; speedup vs baseline: 1.4324x; 1.4324x over previous
//
#include <hip/hip_runtime.h>
#include <hip/hip_bf16.h>

typedef __attribute__((ext_vector_type(8))) short bf16x8_t;
typedef __attribute__((ext_vector_type(4))) float f32x4_t;

#define XP_BYTES 55115776u   // 4*16*58*58*128*2
#define WT_BYTES 4718592u    // 4*2*256*1152*2

typedef __attribute__((address_space(1))) const unsigned int ga_u32_t;
typedef __attribute__((address_space(3))) unsigned int lds_u32_t;

__device__ __forceinline__ void g2l16(const void* g, void* l) {
  __builtin_amdgcn_global_load_lds((ga_u32_t*)g, (lds_u32_t*)l, 16, 0, 0);
}

// ---------------------------------------------------------------------------
// prep_x: x (16,256,56,56) f32  ->  xp (4,16,58,58,128) bf16, inner = hl*64+c
// borders zeroed by hipMemsetAsync before this kernel.
// ---------------------------------------------------------------------------
__global__ __launch_bounds__(256) void prep_x(const float* __restrict__ x,
                                              __hip_bfloat16* __restrict__ xp) {
  __shared__ float ls[64 * 57];
  int blk = blockIdx.x;            // (g, b, h) : 4*16*56 = 3584
  int g = blk / 896;
  int r = blk - g * 896;
  int b = r / 56;
  int h = r - b * 56;
  int tid = threadIdx.x;
  const float* src = x + (size_t)(b * 256 + g * 64) * 3136 + h * 56;
  for (int i = tid; i < 64 * 56; i += 256) {
    int c = i / 56, w = i - c * 56;
    ls[c * 57 + w] = src[(size_t)c * 3136 + w];
  }
  __syncthreads();
  __hip_bfloat16* dst = xp + ((size_t)((g * 16 + b) * 58 + h + 1) * 58 + 1) * 128;
  int wp = tid >> 7;
  int inner = tid & 127;
  int hl = inner >> 6, c = inner & 63;
  for (int w0 = 0; w0 < 56; w0 += 2) {
    int w = w0 + wp;
    float v = ls[c * 57 + w];
    __hip_bfloat16 hi = __float2bfloat16(v);
    __hip_bfloat16 val = hl ? __float2bfloat16(v - __bfloat162float(hi)) : hi;
    dst[(size_t)w * 128 + inner] = val;
  }
}

// ---------------------------------------------------------------------------
// prep_w: weight (256,256,3,3) f32 -> wt[g][sign][oc 0..255][tap][hl][64c]
// integer quant levels 0..3 as bf16 (exact), duplicated for hl=0/1.
// ---------------------------------------------------------------------------
__global__ __launch_bounds__(256) void prep_w(const float* __restrict__ wgt,
                                              const float* __restrict__ wsc,
                                              __hip_bfloat16* __restrict__ wt) {
  int idx = blockIdx.x * 256 + threadIdx.x;   // 589824
  if (idx >= 589824) return;
  int oc = idx / 2304;
  int r = idx - oc * 2304;
  int C = r / 9;
  int tap = r - C * 9;
  int g = C >> 6, c = C & 63;
  float s = wsc[g];
  float rv = wgt[idx] / s;
  float ip = rintf(fminf(fmaxf(rv, 0.f), 3.f));
  float iN = rintf(fminf(fmaxf(-rv, 0.f), 3.f));
  size_t base_p = (size_t)(g * 512 + oc) * 1152 + tap * 128 + c;
  size_t base_n = base_p + (size_t)256 * 1152;
  __hip_bfloat16 vp = __float2bfloat16(ip);
  __hip_bfloat16 vn = __float2bfloat16(iN);
  wt[base_p] = vp;
  wt[base_p + 64] = vp;
  wt[base_n] = vn;
  wt[base_n + 64] = vn;
}

// ---------------------------------------------------------------------------
// Main implicit-GEMM conv, temporal signs. BM=128 (spatial), BN=256 (all oc).
// 512 thr = 8 waves (2M x 4N), per-wave 64x64. K = 144 steps of 64
// (g x sign x tap x hl); quantize boundary every 18 steps (sign 0 adds,
// sign 1 subtracts). Triple-buffered LDS, counted vmcnt(6), setprio MFMA.
// XOR swizzle (slot = chunk ^ (row&7)) on both stage-source and frag-read.
// ---------------------------------------------------------------------------
#define MEMPIN asm volatile("" ::: "memory")
#define BAR __builtin_amdgcn_s_barrier()
#define VMCNT6 asm volatile("s_waitcnt vmcnt(6)" ::: "memory")
#define VMCNT0 asm volatile("s_waitcnt vmcnt(0)" ::: "memory")

__global__ __launch_bounds__(512, 2) void conv_mfma(
    const unsigned short* __restrict__ xp, const unsigned short* __restrict__ wt,
    const float* __restrict__ wsc, const float* __restrict__ psp,
    const float* __restrict__ psn, float* __restrict__ out) {
  // per buffer: A [128 rows][128B] = 16KB at +0, B [256 rows][128B] = 32KB at +16384
  __shared__ char AB[3][49152];                 // 144 KB

  const int bid = blockIdx.x;
  const int wg = (bid & 7) * 49 + (bid >> 3);   // bijective XCD swizzle (392 = 8*49)
  const int mblk = wg;                          // 392 M-tiles, 1 N-tile

  const int tid = threadIdx.x;
  const int wv = tid >> 6;
  const int l = tid & 63;
  const int wr = wv >> 2, wc = wv & 3;

  // ---- staging: thread covers LDS byte tid*16 (+j*8192); row=tid>>3(+64j), slot=tid&7
  const int srow = tid >> 3;
  const unsigned cs16 = (unsigned)(((tid & 7) ^ (srow & 7)) << 4);  // swizzled chunk
  unsigned apix0, apix1, bofs0, bofs1, bofs2, bofs3;
  {
    int m0 = mblk * 128 + srow;
    int b0 = m0 / 3136, hw0 = m0 - b0 * 3136, h0 = hw0 / 56, w0 = hw0 - h0 * 56;
    apix0 = (unsigned)((b0 * 3364 + h0 * 58 + w0) * 256) + cs16;
    int m1 = m0 + 64;
    int b1 = m1 / 3136, hw1 = m1 - b1 * 3136, h1 = hw1 / 56, w1 = hw1 - h1 * 56;
    apix1 = (unsigned)((b1 * 3364 + h1 * 58 + w1) * 256) + cs16;
    bofs0 = (unsigned)(srow * 2304) + cs16;
    bofs1 = bofs0 + 64u * 2304u;
    bofs2 = bofs0 + 128u * 2304u;
    bofs3 = bofs0 + 192u * 2304u;
  }

  // ---- fragment read offsets: row = base + (l&15); chunk = kk*4 + (l>>4)
  const unsigned a_base = (unsigned)((wr * 64 + (l & 15)) * 128);
  const unsigned b_base = (unsigned)(16384 + (wc * 64 + (l & 15)) * 128);
  const unsigned sw0 = (unsigned)((((l >> 4) + 0) ^ (l & 7)) << 4);  // kk0 swz slot
  const unsigned sw1 = (unsigned)((((l >> 4) + 4) ^ (l & 7)) << 4);  // kk1 swz slot

  // ---- scalars preloaded (no vector loads inside the loop)
  float w0s = wsc[0], w1s = wsc[1], w2s = wsc[2], w3s = wsc[3];
  float p0 = psp[0], p1 = psp[1], p2 = psp[2], p3 = psp[3];
  float n0 = psn[0], n1 = psn[1], n2 = psn[2], n3 = psn[3];

  f32x4_t acc[4][4], oacc[4][4];
  const f32x4_t fz = {0.f, 0.f, 0.f, 0.f};
#pragma unroll
  for (int i = 0; i < 4; ++i)
#pragma unroll
    for (int j = 0; j < 4; ++j) { acc[i][j] = fz; oacc[i][j] = fz; }

  const char* xg = (const char*)xp;
  const char* wgp = (const char*)wt;

#define STAGE_A(t2)                                                            \
  {                                                                            \
    const int tt = (t2);                                                       \
    const int g_ = tt / 36;                                                    \
    const int r_ = tt - g_ * 36;                                               \
    const int s18 = (r_ >= 18) ? (r_ - 18) : r_;                               \
    const int tap_ = s18 >> 1, hl_ = s18 & 1;                                  \
    const unsigned at_ = (unsigned)g_ * 13778944u +                            \
                         (unsigned)(((tap_ / 3) * 58 + (tap_ % 3)) * 256) +    \
                         (unsigned)(hl_ << 7);                                 \
    char* lA_ = &AB[tt % 3][0] + (wv << 10);                                   \
    g2l16(xg + apix0 + at_, lA_);                                              \
    g2l16(xg + apix1 + at_, lA_ + 8192);                                       \
  }

#define STAGE_B(t2)                                                            \
  {                                                                            \
    const int tt = (t2);                                                       \
    const int g_ = tt / 36;                                                    \
    const int r_ = tt - g_ * 36;                                               \
    const int sgn_ = (r_ >= 18) ? 1 : 0;                                       \
    const int s18 = r_ - (sgn_ ? 18 : 0);                                      \
    const int tap_ = s18 >> 1, hl_ = s18 & 1;                                  \
    const unsigned bt_ = (unsigned)((g_ * 2 + sgn_) * 589824) +                \
                         (unsigned)((tap_ * 2 + hl_) << 7);                    \
    char* lB_ = &AB[tt % 3][16384] + (wv << 10);                               \
    g2l16(wgp + bofs0 + bt_, lB_);                                             \
    g2l16(wgp + bofs1 + bt_, lB_ + 8192);                                      \
    g2l16(wgp + bofs2 + bt_, lB_ + 16384);                                     \
    g2l16(wgp + bofs3 + bt_, lB_ + 24576);                                     \
  }

#define PHASE_MMA                                                              \
  __builtin_amdgcn_s_setprio(1);                                               \
  _Pragma("unroll") for (int mi = 0; mi < 4; ++mi)                             \
      _Pragma("unroll") for (int ni = 0; ni < 4; ++ni)                         \
          acc[mi][ni] = __builtin_amdgcn_mfma_f32_16x16x32_bf16(               \
              af[mi], bf[ni], acc[mi][ni], 0, 0, 0);                           \
  __builtin_amdgcn_s_setprio(0);

  // ---- prologue: stage steps 0 and 1 (12 loads in flight)
  STAGE_A(0); STAGE_B(0); STAGE_A(1); STAGE_B(1);

  for (int t = 0; t < 144; ++t) {
    if (t == 143) { VMCNT0; } else { VMCNT6; }   // step t's 6 loads complete
    BAR;
    MEMPIN;                                      // no frag reads above the barrier
    const char* buf = &AB[t % 3][0];
    bf16x8_t af[4], bf[4];
    // ---- phase 0 (kk = 0): reads, stage A(t+2), 16 MFMA
#pragma unroll
    for (int mi = 0; mi < 4; ++mi)
      af[mi] = *(const bf16x8_t*)(buf + a_base + mi * 2048 + sw0);
#pragma unroll
    for (int ni = 0; ni < 4; ++ni)
      bf[ni] = *(const bf16x8_t*)(buf + b_base + ni * 2048 + sw0);
    MEMPIN;
    if (t + 2 < 144) { STAGE_A(t + 2); }
    PHASE_MMA;
    // ---- phase 1 (kk = 1): reads, stage B(t+2), 16 MFMA
#pragma unroll
    for (int mi = 0; mi < 4; ++mi)
      af[mi] = *(const bf16x8_t*)(buf + a_base + mi * 2048 + sw1);
#pragma unroll
    for (int ni = 0; ni < 4; ++ni)
      bf[ni] = *(const bf16x8_t*)(buf + b_base + ni * 2048 + sw1);
    MEMPIN;
    if (t + 2 < 144) { STAGE_B(t + 2); }
    PHASE_MMA;

    // ---- group-sign boundary: quantize psums
    if ((t % 18) == 17) {
      int gg = t / 36;
      int sgn = (t / 18) & 1;
      float sw = (gg & 2) ? ((gg & 1) ? w3s : w2s) : ((gg & 1) ? w1s : w0s);
      float sp = (gg & 2) ? ((gg & 1) ? p3 : p2) : ((gg & 1) ? p1 : p0);
      float sn = (gg & 2) ? ((gg & 1) ? n3 : n2) : ((gg & 1) ? n1 : n0);
      float sq = sgn ? sn : sp;
      float rs = sw / sq;
      float sgnmul = sgn ? -1.f : 1.f;
#pragma unroll
      for (int mi = 0; mi < 4; ++mi)
#pragma unroll
        for (int ni = 0; ni < 4; ++ni)
#pragma unroll
          for (int j = 0; j < 4; ++j) {
            float v = acc[mi][ni][j] * rs;
            v = fminf(fmaxf(v, -128.f), 127.f);
            oacc[mi][ni][j] += sgnmul * rintf(v) * sq;
            acc[mi][ni][j] = 0.f;
          }
    }
  }

  // ---- write: col = oc, row = spatial m
#pragma unroll
  for (int ni = 0; ni < 4; ++ni) {
    int oc = wc * 64 + ni * 16 + (l & 15);
#pragma unroll
    for (int mi = 0; mi < 4; ++mi) {
      int m0 = mblk * 128 + wr * 64 + mi * 16 + ((l >> 4) << 2);
#pragma unroll
      for (int j = 0; j < 4; ++j) {
        int m = m0 + j;
        int b = m / 3136;
        int hw = m - b * 3136;
        out[(size_t)((b << 8) + oc) * 3136 + hw] = oacc[mi][ni][j];
      }
    }
  }
#undef STAGE_A
#undef STAGE_B
#undef PHASE_MMA
}

// ---------------------------------------------------------------------------
// Fallback (ws too small): direct conv with inline weight quantization.
// ---------------------------------------------------------------------------
__global__ __launch_bounds__(256) void naive_conv(
    const float* __restrict__ x, const float* __restrict__ wgt,
    const float* __restrict__ wsc, const float* __restrict__ psp,
    const float* __restrict__ psn, float* __restrict__ out) {
  int idx = blockIdx.x * 256 + threadIdx.x;
  if (idx >= 12845056) return;
  int b = idx / 802816;
  int r = idx - b * 802816;
  int oc = r / 3136;
  int hw = r - oc * 3136;
  int h = hw / 56, w = hw - (hw / 56) * 56;
  float o = 0.f;
  for (int g = 0; g < 4; ++g) {
    float sw = wsc[g];
    float inv = 1.f / sw;
    float pp = 0.f, pn = 0.f;
    for (int tap = 0; tap < 9; ++tap) {
      int y = h + tap / 3 - 1, xx = w + tap % 3 - 1;
      if (y < 0 || y > 55 || xx < 0 || xx > 55) continue;
      const float* xr = x + (size_t)(b * 256 + g * 64) * 3136 + y * 56 + xx;
      const float* wrr = wgt + (size_t)oc * 2304 + (size_t)(g * 64) * 9 + tap;
      for (int c = 0; c < 64; ++c) {
        float xv = xr[(size_t)c * 3136];
        float rv = wrr[c * 9] * inv;
        pp += xv * rintf(fminf(fmaxf(rv, 0.f), 3.f));
        pn += xv * rintf(fminf(fmaxf(-rv, 0.f), 3.f));
      }
    }
    float sp = psp[g], sn = psn[g];
    o += rintf(fminf(fmaxf(pp * (sw / sp), -128.f), 127.f)) * sp;
    o -= rintf(fminf(fmaxf(pn * (sw / sn), -128.f), 127.f)) * sn;
  }
  out[idx] = o;
}

extern "C" void kernel_launch(void* const* d_in, const int* in_sizes, int n_in,
                              void* d_out, int out_size, void* d_ws, size_t ws_size,
                              hipStream_t stream) {
  const float* x = (const float*)d_in[0];
  const float* wgt = (const float*)d_in[1];
  const float* wsc = (const float*)d_in[2];
  const float* psp = (const float*)d_in[3];
  const float* psn = (const float*)d_in[4];
  float* out = (float*)d_out;

  if (ws_size >= (size_t)XP_BYTES + (size_t)WT_BYTES) {
    unsigned short* xpw = (unsigned short*)d_ws;
    unsigned short* wtw = (unsigned short*)((char*)d_ws + XP_BYTES);
    hipMemsetAsync(d_ws, 0, XP_BYTES, stream);
    prep_x<<<3584, 256, 0, stream>>>(x, (__hip_bfloat16*)xpw);
    prep_w<<<2304, 256, 0, stream>>>(wgt, wsc, (__hip_bfloat16*)wtw);
    conv_mfma<<<392, 512, 0, stream>>>(xpw, wtw, wsc, psp, psn, out);
  } else {
    naive_conv<<<(12845056 + 255) / 256, 256, 0, stream>>>(x, wgt, wsc, psp, psn, out);
  }
}